// Round 1
// baseline (823.741 us; speedup 1.0000x reference)
//
#include <hip/hip_runtime.h>
#include <hip/hip_bf16.h>

#define G_DIM 64
#define F_DIM 128
#define C_DIM 4

// meta layout in ws (uint32 slots)
#define META_COUNTS 0   // 4
#define META_BASES  4   // 5 (exclusive prefix, [4]=E)
#define META_TSTART 9   // 5 (tile-base prefix, [4]=total tiles)
#define META_CURS   14  // 4 (scatter cursors)
#define IDX_OFF     32  // int32 index list starts here

typedef __bf16 bf16x8 __attribute__((ext_vector_type(8)));
typedef float  f32x4  __attribute__((ext_vector_type(4)));

__device__ inline unsigned short f2bf(float f) {
    union { float f; unsigned u; } v; v.f = f;
    unsigned r = v.u + 0x7FFFu + ((v.u >> 16) & 1u);  // RTNE
    return (unsigned short)(r >> 16);
}

__device__ inline float ssp(float x) {
    // softplus(x) - log(2), numerically stable
    float t = __expf(-fabsf(x));
    return fmaxf(x, 0.f) + __logf(1.f + t) - 0.69314718055994531f;
}

__global__ void k_zero(unsigned* meta) {
    if (threadIdx.x < 32) meta[threadIdx.x] = 0;
}

__global__ void k_count(const int* __restrict__ colors, int E, unsigned* meta) {
    int e = blockIdx.x * 256 + threadIdx.x;
    int c = (e < E) ? colors[e] : -1;
#pragma unroll
    for (int cc = 0; cc < C_DIM; ++cc) {
        unsigned long long m = __ballot(c == cc);
        if ((threadIdx.x & 63) == 0 && m)
            atomicAdd(&meta[META_COUNTS + cc], (unsigned)__popcll(m));
    }
}

__global__ void k_prefix(unsigned* meta) {
    if (threadIdx.x == 0) {
        unsigned bsum = 0, tsum = 0;
        for (int c = 0; c < C_DIM; ++c) {
            meta[META_BASES + c] = bsum;
            meta[META_CURS + c] = bsum;
            meta[META_TSTART + c] = tsum;
            bsum += meta[META_COUNTS + c];
            tsum += (meta[META_COUNTS + c] + 63) >> 6;
        }
        meta[META_BASES + 4] = bsum;
        meta[META_TSTART + 4] = tsum;
    }
}

// Convert weights to bf16, transposed for B-fragment loads:
// w1t[c][n][k] = W1[c][k][n]  (n=0..127 out col, k=0..63)
// w2t[c][n][k] = W2[c][k][n]  (n=0..127 out col, k=0..127)
__global__ void k_convert(const float* __restrict__ W1, const float* __restrict__ W2,
                          unsigned short* __restrict__ w1t, unsigned short* __restrict__ w2t) {
    int i = blockIdx.x * 256 + threadIdx.x;
    if (i < C_DIM * F_DIM * G_DIM) {
        int k = i % G_DIM, n = (i / G_DIM) % F_DIM, c = i / (G_DIM * F_DIM);
        w1t[i] = f2bf(W1[(c * G_DIM + k) * F_DIM + n]);
    }
    if (i < C_DIM * F_DIM * F_DIM) {
        int k = i % F_DIM, n = (i / F_DIM) % F_DIM, c = i / (F_DIM * F_DIM);
        w2t[i] = f2bf(W2[(c * F_DIM + k) * F_DIM + n]);
    }
}

__global__ void k_scatter(const int* __restrict__ colors, int E, unsigned* meta, int* idx) {
    int e = blockIdx.x * 256 + threadIdx.x;
    int lane = threadIdx.x & 63;
    int c = (e < E) ? colors[e] : -1;
#pragma unroll
    for (int cc = 0; cc < C_DIM; ++cc) {
        unsigned long long m = __ballot(c == cc);
        if (!m) continue;
        int leader = __ffsll(m) - 1;
        unsigned base = 0;
        if (lane == leader) base = atomicAdd(&meta[META_CURS + cc], (unsigned)__popcll(m));
        base = __shfl(base, leader, 64);
        if (c == cc) {
            unsigned off = __popcll(m & ((1ull << lane) - 1ull));
            idx[base + off] = e;
        }
    }
}

// Main fused MLP: one block = 64 edges of a single color.
// 256 threads = 4 waves; wave w owns output cols [w*32, w*32+32).
__global__ __launch_bounds__(256, 2) void mlp_main(
    const float* __restrict__ ea, const float* __restrict__ b1,
    const float* __restrict__ b2, const unsigned short* __restrict__ w1t,
    const unsigned short* __restrict__ w2t, const unsigned* __restrict__ meta,
    const int* __restrict__ idx, float* __restrict__ out) {
    __shared__ unsigned short A[64][72];    // edges x G, pad 64->72 (bank spread)
    __shared__ unsigned short H[64][136];   // edges x F, pad 128->136
    __shared__ int rowmap[64];

    unsigned b = blockIdx.x;
    if (b >= meta[META_TSTART + 4]) return;
    int c = 0;
    if (b >= meta[META_TSTART + 1]) c = 1;
    if (b >= meta[META_TSTART + 2]) c = 2;
    if (b >= meta[META_TSTART + 3]) c = 3;
    int t = (int)(b - meta[META_TSTART + c]);
    int segBase = (int)meta[META_BASES + c];
    int segCnt  = (int)meta[META_COUNTS + c];
    int row0 = t * 64;
    int nrows = segCnt - row0; if (nrows > 64) nrows = 64;

    int tid = threadIdx.x;
    if (tid < 64) rowmap[tid] = (tid < nrows) ? idx[segBase + row0 + tid] : -1;
    __syncthreads();

    // ---- stage A (gather edge rows, f32 -> bf16) ----
    {
        int r = tid >> 2, q = tid & 3;   // row, 16-float chunk
        int e = rowmap[r];
        unsigned short tmp[16];
        if (e >= 0) {
            const float4* src = (const float4*)(ea + (size_t)e * G_DIM + q * 16);
#pragma unroll
            for (int i = 0; i < 4; ++i) {
                float4 v = src[i];
                tmp[i * 4 + 0] = f2bf(v.x); tmp[i * 4 + 1] = f2bf(v.y);
                tmp[i * 4 + 2] = f2bf(v.z); tmp[i * 4 + 3] = f2bf(v.w);
            }
        } else {
#pragma unroll
            for (int i = 0; i < 16; ++i) tmp[i] = 0;
        }
        *(uint4*)&A[r][q * 16]     = *(uint4*)&tmp[0];
        *(uint4*)&A[r][q * 16 + 8] = *(uint4*)&tmp[8];
    }

    int w = tid >> 6, lane = tid & 63;
    int l15 = lane & 15, l4 = lane >> 4;

    // ---- weight B-fragments into registers (L2-hot bf16 ws copies) ----
    bf16x8 fB1[2][2];   // [nt][ks]
    bf16x8 fB2[2][4];
    float bias1[2], bias2[2];
#pragma unroll
    for (int nt = 0; nt < 2; ++nt) {
        int n = w * 32 + nt * 16 + l15;
        bias1[nt] = b1[c * F_DIM + n];
        bias2[nt] = b2[c * F_DIM + n];
#pragma unroll
        for (int ks = 0; ks < 2; ++ks)
            fB1[nt][ks] = *(const bf16x8*)(w1t + ((size_t)(c * F_DIM + n) * G_DIM + ks * 32 + l4 * 8));
#pragma unroll
        for (int ks = 0; ks < 4; ++ks)
            fB2[nt][ks] = *(const bf16x8*)(w2t + ((size_t)(c * F_DIM + n) * F_DIM + ks * 32 + l4 * 8));
    }
    __syncthreads();  // A staged

    // ---- GEMM1: h = A @ W1 ----
    f32x4 acc[4][2];
#pragma unroll
    for (int mt = 0; mt < 4; ++mt)
#pragma unroll
        for (int nt = 0; nt < 2; ++nt) acc[mt][nt] = (f32x4){0.f, 0.f, 0.f, 0.f};
#pragma unroll
    for (int ks = 0; ks < 2; ++ks) {
#pragma unroll
        for (int mt = 0; mt < 4; ++mt) {
            bf16x8 a = *(const bf16x8*)&A[mt * 16 + l15][ks * 32 + l4 * 8];
            acc[mt][0] = __builtin_amdgcn_mfma_f32_16x16x32_bf16(a, fB1[0][ks], acc[mt][0], 0, 0, 0);
            acc[mt][1] = __builtin_amdgcn_mfma_f32_16x16x32_bf16(a, fB1[1][ks], acc[mt][1], 0, 0, 0);
        }
    }

    // ---- bias + shifted-softplus -> H (bf16) ----
#pragma unroll
    for (int mt = 0; mt < 4; ++mt)
#pragma unroll
        for (int nt = 0; nt < 2; ++nt)
#pragma unroll
            for (int r = 0; r < 4; ++r) {
                float v = acc[mt][nt][r] + bias1[nt];
                H[mt * 16 + l4 * 4 + r][w * 32 + nt * 16 + l15] = f2bf(ssp(v));
            }
    __syncthreads();

    // ---- GEMM2: y = H @ W2 ----
#pragma unroll
    for (int mt = 0; mt < 4; ++mt)
#pragma unroll
        for (int nt = 0; nt < 2; ++nt) acc[mt][nt] = (f32x4){0.f, 0.f, 0.f, 0.f};
#pragma unroll
    for (int ks = 0; ks < 4; ++ks) {
#pragma unroll
        for (int mt = 0; mt < 4; ++mt) {
            bf16x8 a = *(const bf16x8*)&H[mt * 16 + l15][ks * 32 + l4 * 8];
            acc[mt][0] = __builtin_amdgcn_mfma_f32_16x16x32_bf16(a, fB2[0][ks], acc[mt][0], 0, 0, 0);
            acc[mt][1] = __builtin_amdgcn_mfma_f32_16x16x32_bf16(a, fB2[1][ks], acc[mt][1], 0, 0, 0);
        }
    }

    // ---- bias + scatter to out ----
#pragma unroll
    for (int mt = 0; mt < 4; ++mt) {
#pragma unroll
        for (int r = 0; r < 4; ++r) {
            int e = rowmap[mt * 16 + l4 * 4 + r];
            if (e >= 0) {
                size_t base = (size_t)e * F_DIM + w * 32 + l15;
                out[base]      = acc[mt][0][r] + bias2[0];
                out[base + 16] = acc[mt][1][r] + bias2[1];
            }
        }
    }
}

// Correct-but-slow fallback if ws is too small (insurance only).
__global__ void fallback(const float* __restrict__ ea, const int* __restrict__ colors,
                         const float* __restrict__ W1, const float* __restrict__ b1,
                         const float* __restrict__ W2, const float* __restrict__ b2,
                         float* __restrict__ out, int E) {
    __shared__ float sh[4][F_DIM + G_DIM];
    int w = threadIdx.x >> 6, lane = threadIdx.x & 63;
    int e = blockIdx.x * 4 + w;
    bool valid = (e < E);
    int ec = valid ? e : 0;
    int c = colors[ec];
    float* hv = sh[w];
    float* av = sh[w] + F_DIM;
    av[lane] = ea[(size_t)ec * G_DIM + lane];
    __syncthreads();
    for (int f = lane; f < F_DIM; f += 64) {
        float s = b1[c * F_DIM + f];
        for (int g = 0; g < G_DIM; ++g) s += av[g] * W1[(c * G_DIM + g) * F_DIM + f];
        hv[f] = ssp(s);
    }
    __syncthreads();
    for (int f = lane; f < F_DIM; f += 64) {
        float s = b2[c * F_DIM + f];
        for (int k = 0; k < F_DIM; ++k) s += hv[k] * W2[(c * F_DIM + k) * F_DIM + f];
        if (valid) out[(size_t)e * F_DIM + f] = s;
    }
}

extern "C" void kernel_launch(void* const* d_in, const int* in_sizes, int n_in,
                              void* d_out, int out_size, void* d_ws, size_t ws_size,
                              hipStream_t stream) {
    const float* ea     = (const float*)d_in[0];
    const int*   colors = (const int*)d_in[1];
    const float* W1     = (const float*)d_in[2];
    const float* b1     = (const float*)d_in[3];
    const float* W2     = (const float*)d_in[4];
    const float* b2     = (const float*)d_in[5];
    float* out = (float*)d_out;
    int E = in_sizes[1];

    size_t need = (size_t)(IDX_OFF + E) * 4 +
                  (size_t)(C_DIM * F_DIM * G_DIM + C_DIM * F_DIM * F_DIM) * 2;
    if (ws_size < need) {
        int blocks = (E + 3) / 4;
        fallback<<<blocks, 256, 0, stream>>>(ea, colors, W1, b1, W2, b2, out, E);
        return;
    }

    unsigned* meta = (unsigned*)d_ws;
    int* idx = (int*)d_ws + IDX_OFF;
    unsigned short* w1t = (unsigned short*)((char*)d_ws + (size_t)(IDX_OFF + E) * 4);
    unsigned short* w2t = w1t + C_DIM * F_DIM * G_DIM;

    int g1 = (E + 255) / 256;
    k_zero<<<1, 64, 0, stream>>>(meta);
    k_count<<<g1, 256, 0, stream>>>(colors, E, meta);
    k_prefix<<<1, 64, 0, stream>>>(meta);
    k_convert<<<256, 256, 0, stream>>>(W1, W2, w1t, w2t);
    k_scatter<<<g1, 256, 0, stream>>>(colors, E, meta, idx);
    int g4 = (E + 63) / 64 + C_DIM;
    mlp_main<<<g4, 256, 0, stream>>>(ea, b1, b2, w1t, w2t, meta, idx, out);
}

// Round 2
// 125.984 us; speedup vs baseline: 6.5385x; 6.5385x over previous
//
#include <hip/hip_runtime.h>
#include <hip/hip_bf16.h>

#define G_DIM 64
#define F_DIM 128
#define C_DIM 4
#define NB    512   // histogram/scatter blocks (must be multiple of 64)

// meta layout in ws (uint32 slots)
#define META_COUNTS 0   // 4
#define META_BASES  4   // 5 (exclusive prefix, [4]=E)
#define META_TSTART 9   // 5 (tile-base prefix, [4]=total tiles)
#define BH_OFF      32          // block histograms: NB*4 uint32
#define IDX_OFF     (32 + NB*4) // int32 index list starts here

typedef __bf16 bf16x8 __attribute__((ext_vector_type(8)));
typedef float  f32x4  __attribute__((ext_vector_type(4)));

__device__ inline unsigned short f2bf(float f) {
    union { float f; unsigned u; } v; v.f = f;
    unsigned r = v.u + 0x7FFFu + ((v.u >> 16) & 1u);  // RTNE
    return (unsigned short)(r >> 16);
}

__device__ inline float ssp(float x) {
    // softplus(x) - log(2), numerically stable
    float t = __expf(-fabsf(x));
    return fmaxf(x, 0.f) + __logf(1.f + t) - 0.69314718055994531f;
}

// ---- per-block histogram (no global atomics) ----
__global__ void k_hist(const int* __restrict__ colors, int E, int CH,
                       unsigned* __restrict__ bh) {
    __shared__ unsigned h[C_DIM];
    int tid = threadIdx.x;
    if (tid < C_DIM) h[tid] = 0;
    __syncthreads();
    int lo = blockIdx.x * CH, hi = lo + CH; if (hi > E) hi = E;
    int lane = tid & 63;
    for (int i0 = lo; i0 < hi; i0 += 256) {
        int i = i0 + tid;
        int c = (i < hi) ? colors[i] : -1;
#pragma unroll
        for (int cc = 0; cc < C_DIM; ++cc) {
            unsigned long long m = __ballot(c == cc);
            if (lane == 0 && m) atomicAdd(&h[cc], (unsigned)__popcll(m));
        }
    }
    __syncthreads();
    if (tid < C_DIM) bh[blockIdx.x * C_DIM + tid] = h[tid];
}

// ---- scan block histograms -> per-block bases + global meta ----
__global__ void k_scan(unsigned* __restrict__ meta, unsigned* __restrict__ bh) {
    __shared__ unsigned counts[C_DIM], bases[C_DIM + 1];
    int tid = threadIdx.x, w = tid >> 6, lane = tid & 63;
    unsigned run = 0;
    for (int b0 = 0; b0 < NB; b0 += 64) {
        int b = b0 + lane;
        unsigned v = bh[b * C_DIM + w];
        unsigned s = v;
#pragma unroll
        for (int d = 1; d < 64; d <<= 1) {
            unsigned t = __shfl_up(s, d, 64);
            if (lane >= d) s += t;
        }
        bh[b * C_DIM + w] = run + s - v;       // exclusive within color
        run += __shfl(s, 63, 64);
    }
    if (lane == 0) counts[w] = run;
    __syncthreads();
    if (tid == 0) {
        unsigned bsum = 0, tsum = 0;
        for (int c = 0; c < C_DIM; ++c) {
            bases[c] = bsum;
            meta[META_BASES + c] = bsum;
            meta[META_COUNTS + c] = counts[c];
            meta[META_TSTART + c] = tsum;
            bsum += counts[c];
            tsum += (counts[c] + 63) >> 6;
        }
        bases[C_DIM] = bsum;
        meta[META_BASES + C_DIM] = bsum;
        meta[META_TSTART + C_DIM] = tsum;
    }
    __syncthreads();
    unsigned base = bases[w];
    for (int b0 = 0; b0 < NB; b0 += 64) bh[(b0 + lane) * C_DIM + w] += base;
}

// ---- scatter edge indices using per-block bases (LDS cursors only) ----
__global__ void k_scatter2(const int* __restrict__ colors, int E, int CH,
                           const unsigned* __restrict__ bh, int* __restrict__ idx) {
    __shared__ unsigned cur[C_DIM];
    int tid = threadIdx.x;
    if (tid < C_DIM) cur[tid] = bh[blockIdx.x * C_DIM + tid];
    __syncthreads();
    int lo = blockIdx.x * CH, hi = lo + CH; if (hi > E) hi = E;
    int lane = tid & 63;
    for (int i0 = lo; i0 < hi; i0 += 256) {
        int i = i0 + tid;
        int c = (i < hi) ? colors[i] : -1;
#pragma unroll
        for (int cc = 0; cc < C_DIM; ++cc) {
            unsigned long long m = __ballot(c == cc);
            if (!m) continue;
            int leader = __ffsll(m) - 1;
            unsigned base = 0;
            if (lane == leader) base = atomicAdd(&cur[cc], (unsigned)__popcll(m));
            base = __shfl(base, leader, 64);
            if (c == cc) {
                unsigned off = __popcll(m & ((1ull << lane) - 1ull));
                idx[base + off] = i;
            }
        }
    }
}

// Convert weights to bf16, transposed for B-fragment loads:
// w1t[c][n][k] = W1[c][k][n]  (n=0..127 out col, k=0..63)
// w2t[c][n][k] = W2[c][k][n]  (n=0..127 out col, k=0..127)
__global__ void k_convert(const float* __restrict__ W1, const float* __restrict__ W2,
                          unsigned short* __restrict__ w1t, unsigned short* __restrict__ w2t) {
    int i = blockIdx.x * 256 + threadIdx.x;
    if (i < C_DIM * F_DIM * G_DIM) {
        int k = i % G_DIM, n = (i / G_DIM) % F_DIM, c = i / (G_DIM * F_DIM);
        w1t[i] = f2bf(W1[(c * G_DIM + k) * F_DIM + n]);
    }
    if (i < C_DIM * F_DIM * F_DIM) {
        int k = i % F_DIM, n = (i / F_DIM) % F_DIM, c = i / (F_DIM * F_DIM);
        w2t[i] = f2bf(W2[(c * F_DIM + k) * F_DIM + n]);
    }
}

// Main fused MLP: one block = 64 edges of a single color.
// 256 threads = 4 waves; wave w owns output cols [w*32, w*32+32).
__global__ __launch_bounds__(256, 2) void mlp_main(
    const float* __restrict__ ea, const float* __restrict__ b1,
    const float* __restrict__ b2, const unsigned short* __restrict__ w1t,
    const unsigned short* __restrict__ w2t, const unsigned* __restrict__ meta,
    const int* __restrict__ idx, float* __restrict__ out) {
    __shared__ unsigned short A[64][72];    // edges x G, pad 64->72 (bank spread)
    __shared__ unsigned short H[64][136];   // edges x F, pad 128->136
    __shared__ int rowmap[64];

    unsigned b = blockIdx.x;
    if (b >= meta[META_TSTART + C_DIM]) return;
    int c = 0;
    if (b >= meta[META_TSTART + 1]) c = 1;
    if (b >= meta[META_TSTART + 2]) c = 2;
    if (b >= meta[META_TSTART + 3]) c = 3;
    int t = (int)(b - meta[META_TSTART + c]);
    int segBase = (int)meta[META_BASES + c];
    int segCnt  = (int)meta[META_COUNTS + c];
    int row0 = t * 64;
    int nrows = segCnt - row0; if (nrows > 64) nrows = 64;

    int tid = threadIdx.x;
    if (tid < 64) rowmap[tid] = (tid < nrows) ? idx[segBase + row0 + tid] : -1;
    __syncthreads();

    // ---- stage A (gather edge rows, f32 -> bf16) ----
    {
        int r = tid >> 2, q = tid & 3;   // row, 16-float chunk
        int e = rowmap[r];
        unsigned short tmp[16];
        if (e >= 0) {
            const float4* src = (const float4*)(ea + (size_t)e * G_DIM + q * 16);
#pragma unroll
            for (int i = 0; i < 4; ++i) {
                float4 v = src[i];
                tmp[i * 4 + 0] = f2bf(v.x); tmp[i * 4 + 1] = f2bf(v.y);
                tmp[i * 4 + 2] = f2bf(v.z); tmp[i * 4 + 3] = f2bf(v.w);
            }
        } else {
#pragma unroll
            for (int i = 0; i < 16; ++i) tmp[i] = 0;
        }
        *(uint4*)&A[r][q * 16]     = *(uint4*)&tmp[0];
        *(uint4*)&A[r][q * 16 + 8] = *(uint4*)&tmp[8];
    }

    int w = tid >> 6, lane = tid & 63;
    int l15 = lane & 15, l4 = lane >> 4;

    // ---- weight B-fragments into registers (L2-hot bf16 ws copies) ----
    bf16x8 fB1[2][2];   // [nt][ks]
    bf16x8 fB2[2][4];
    float bias1[2], bias2[2];
#pragma unroll
    for (int nt = 0; nt < 2; ++nt) {
        int n = w * 32 + nt * 16 + l15;
        bias1[nt] = b1[c * F_DIM + n];
        bias2[nt] = b2[c * F_DIM + n];
#pragma unroll
        for (int ks = 0; ks < 2; ++ks)
            fB1[nt][ks] = *(const bf16x8*)(w1t + ((size_t)(c * F_DIM + n) * G_DIM + ks * 32 + l4 * 8));
#pragma unroll
        for (int ks = 0; ks < 4; ++ks)
            fB2[nt][ks] = *(const bf16x8*)(w2t + ((size_t)(c * F_DIM + n) * F_DIM + ks * 32 + l4 * 8));
    }
    __syncthreads();  // A staged

    // ---- GEMM1: h = A @ W1 ----
    f32x4 acc[4][2];
#pragma unroll
    for (int mt = 0; mt < 4; ++mt)
#pragma unroll
        for (int nt = 0; nt < 2; ++nt) acc[mt][nt] = (f32x4){0.f, 0.f, 0.f, 0.f};
#pragma unroll
    for (int ks = 0; ks < 2; ++ks) {
#pragma unroll
        for (int mt = 0; mt < 4; ++mt) {
            bf16x8 a = *(const bf16x8*)&A[mt * 16 + l15][ks * 32 + l4 * 8];
            acc[mt][0] = __builtin_amdgcn_mfma_f32_16x16x32_bf16(a, fB1[0][ks], acc[mt][0], 0, 0, 0);
            acc[mt][1] = __builtin_amdgcn_mfma_f32_16x16x32_bf16(a, fB1[1][ks], acc[mt][1], 0, 0, 0);
        }
    }

    // ---- bias + shifted-softplus -> H (bf16) ----
#pragma unroll
    for (int mt = 0; mt < 4; ++mt)
#pragma unroll
        for (int nt = 0; nt < 2; ++nt)
#pragma unroll
            for (int r = 0; r < 4; ++r) {
                float v = acc[mt][nt][r] + bias1[nt];
                H[mt * 16 + l4 * 4 + r][w * 32 + nt * 16 + l15] = f2bf(ssp(v));
            }
    __syncthreads();

    // ---- GEMM2: y = H @ W2 ----
#pragma unroll
    for (int mt = 0; mt < 4; ++mt)
#pragma unroll
        for (int nt = 0; nt < 2; ++nt) acc[mt][nt] = (f32x4){0.f, 0.f, 0.f, 0.f};
#pragma unroll
    for (int ks = 0; ks < 4; ++ks) {
#pragma unroll
        for (int mt = 0; mt < 4; ++mt) {
            bf16x8 a = *(const bf16x8*)&H[mt * 16 + l15][ks * 32 + l4 * 8];
            acc[mt][0] = __builtin_amdgcn_mfma_f32_16x16x32_bf16(a, fB2[0][ks], acc[mt][0], 0, 0, 0);
            acc[mt][1] = __builtin_amdgcn_mfma_f32_16x16x32_bf16(a, fB2[1][ks], acc[mt][1], 0, 0, 0);
        }
    }

    // ---- bias + scatter to out ----
#pragma unroll
    for (int mt = 0; mt < 4; ++mt) {
#pragma unroll
        for (int r = 0; r < 4; ++r) {
            int e = rowmap[mt * 16 + l4 * 4 + r];
            if (e >= 0) {
                size_t base = (size_t)e * F_DIM + w * 32 + l15;
                out[base]      = acc[mt][0][r] + bias2[0];
                out[base + 16] = acc[mt][1][r] + bias2[1];
            }
        }
    }
}

// Correct-but-slow fallback if ws is too small (insurance only).
__global__ void fallback(const float* __restrict__ ea, const int* __restrict__ colors,
                         const float* __restrict__ W1, const float* __restrict__ b1,
                         const float* __restrict__ W2, const float* __restrict__ b2,
                         float* __restrict__ out, int E) {
    __shared__ float sh[4][F_DIM + G_DIM];
    int w = threadIdx.x >> 6, lane = threadIdx.x & 63;
    int e = blockIdx.x * 4 + w;
    bool valid = (e < E);
    int ec = valid ? e : 0;
    int c = colors[ec];
    float* hv = sh[w];
    float* av = sh[w] + F_DIM;
    av[lane] = ea[(size_t)ec * G_DIM + lane];
    __syncthreads();
    for (int f = lane; f < F_DIM; f += 64) {
        float s = b1[c * F_DIM + f];
        for (int g = 0; g < G_DIM; ++g) s += av[g] * W1[(c * G_DIM + g) * F_DIM + f];
        hv[f] = ssp(s);
    }
    __syncthreads();
    for (int f = lane; f < F_DIM; f += 64) {
        float s = b2[c * F_DIM + f];
        for (int k = 0; k < F_DIM; ++k) s += hv[k] * W2[(c * F_DIM + k) * F_DIM + f];
        if (valid) out[(size_t)e * F_DIM + f] = s;
    }
}

extern "C" void kernel_launch(void* const* d_in, const int* in_sizes, int n_in,
                              void* d_out, int out_size, void* d_ws, size_t ws_size,
                              hipStream_t stream) {
    const float* ea     = (const float*)d_in[0];
    const int*   colors = (const int*)d_in[1];
    const float* W1     = (const float*)d_in[2];
    const float* b1     = (const float*)d_in[3];
    const float* W2     = (const float*)d_in[4];
    const float* b2     = (const float*)d_in[5];
    float* out = (float*)d_out;
    int E = in_sizes[1];

    size_t need = (size_t)(IDX_OFF + E) * 4 +
                  (size_t)(C_DIM * F_DIM * G_DIM + C_DIM * F_DIM * F_DIM) * 2;
    if (ws_size < need) {
        int blocks = (E + 3) / 4;
        fallback<<<blocks, 256, 0, stream>>>(ea, colors, W1, b1, W2, b2, out, E);
        return;
    }

    unsigned* meta = (unsigned*)d_ws;
    unsigned* bh   = (unsigned*)d_ws + BH_OFF;
    int* idx = (int*)d_ws + IDX_OFF;
    unsigned short* w1t = (unsigned short*)((char*)d_ws + (size_t)(IDX_OFF + E) * 4);
    unsigned short* w2t = w1t + C_DIM * F_DIM * G_DIM;

    int CH = (E + NB - 1) / NB;
    k_hist<<<NB, 256, 0, stream>>>(colors, E, CH, bh);
    k_scan<<<1, 256, 0, stream>>>(meta, bh);
    k_convert<<<256, 256, 0, stream>>>(W1, W2, w1t, w2t);
    k_scatter2<<<NB, 256, 0, stream>>>(colors, E, CH, bh, idx);
    int g4 = (E + 63) / 64 + C_DIM;
    mlp_main<<<g4, 256, 0, stream>>>(ea, b1, b2, w1t, w2t, meta, idx, out);
}

// Round 3
// 116.366 us; speedup vs baseline: 7.0789x; 1.0827x over previous
//
#include <hip/hip_runtime.h>
#include <hip/hip_bf16.h>

#define G_DIM 64
#define F_DIM 128
#define C_DIM 4
#define NB    512   // histogram/scatter blocks (must be multiple of 64)

// meta layout in ws (uint32 slots)
#define META_COUNTS 0   // 4
#define META_BASES  4   // 5 (exclusive prefix, [4]=E)
#define META_TSTART 9   // 5 (tile-base prefix, [4]=total tiles)
#define BH_OFF      32          // block histograms: NB*4 uint32
#define IDX_OFF     (32 + NB*4) // int32 index list starts here

typedef __bf16 bf16x8 __attribute__((ext_vector_type(8)));
typedef float  f32x4  __attribute__((ext_vector_type(4)));

__device__ inline unsigned short f2bf(float f) {
    union { float f; unsigned u; } v; v.f = f;
    unsigned r = v.u + 0x7FFFu + ((v.u >> 16) & 1u);  // RTNE
    return (unsigned short)(r >> 16);
}

__device__ inline float ssp(float x) {
    // softplus(x) - log(2), numerically stable
    float t = __expf(-fabsf(x));
    return fmaxf(x, 0.f) + __logf(1.f + t) - 0.69314718055994531f;
}

// ---- per-block histogram (no global atomics) ----
__global__ void k_hist(const int* __restrict__ colors, int E, int CH,
                       unsigned* __restrict__ bh) {
    __shared__ unsigned h[C_DIM];
    int tid = threadIdx.x;
    if (tid < C_DIM) h[tid] = 0;
    __syncthreads();
    int lo = blockIdx.x * CH, hi = lo + CH; if (hi > E) hi = E;
    int lane = tid & 63;
    for (int i0 = lo; i0 < hi; i0 += 256) {
        int i = i0 + tid;
        int c = (i < hi) ? colors[i] : -1;
#pragma unroll
        for (int cc = 0; cc < C_DIM; ++cc) {
            unsigned long long m = __ballot(c == cc);
            if (lane == 0 && m) atomicAdd(&h[cc], (unsigned)__popcll(m));
        }
    }
    __syncthreads();
    if (tid < C_DIM) bh[blockIdx.x * C_DIM + tid] = h[tid];
}

// ---- scan block histograms -> per-block bases + global meta ----
__global__ void k_scan(unsigned* __restrict__ meta, unsigned* __restrict__ bh) {
    __shared__ unsigned counts[C_DIM], bases[C_DIM + 1];
    int tid = threadIdx.x, w = tid >> 6, lane = tid & 63;
    unsigned run = 0;
    for (int b0 = 0; b0 < NB; b0 += 64) {
        int b = b0 + lane;
        unsigned v = bh[b * C_DIM + w];
        unsigned s = v;
#pragma unroll
        for (int d = 1; d < 64; d <<= 1) {
            unsigned t = __shfl_up(s, d, 64);
            if (lane >= d) s += t;
        }
        bh[b * C_DIM + w] = run + s - v;       // exclusive within color
        run += __shfl(s, 63, 64);
    }
    if (lane == 0) counts[w] = run;
    __syncthreads();
    if (tid == 0) {
        unsigned bsum = 0, tsum = 0;
        for (int c = 0; c < C_DIM; ++c) {
            bases[c] = bsum;
            meta[META_BASES + c] = bsum;
            meta[META_COUNTS + c] = counts[c];
            meta[META_TSTART + c] = tsum;
            bsum += counts[c];
            tsum += (counts[c] + 63) >> 6;
        }
        bases[C_DIM] = bsum;
        meta[META_BASES + C_DIM] = bsum;
        meta[META_TSTART + C_DIM] = tsum;
    }
    __syncthreads();
    unsigned base = bases[w];
    for (int b0 = 0; b0 < NB; b0 += 64) bh[(b0 + lane) * C_DIM + w] += base;
}

// ---- scatter edge indices using per-block bases (LDS cursors only) ----
__global__ void k_scatter2(const int* __restrict__ colors, int E, int CH,
                           const unsigned* __restrict__ bh, int* __restrict__ idx) {
    __shared__ unsigned cur[C_DIM];
    int tid = threadIdx.x;
    if (tid < C_DIM) cur[tid] = bh[blockIdx.x * C_DIM + tid];
    __syncthreads();
    int lo = blockIdx.x * CH, hi = lo + CH; if (hi > E) hi = E;
    int lane = tid & 63;
    for (int i0 = lo; i0 < hi; i0 += 256) {
        int i = i0 + tid;
        int c = (i < hi) ? colors[i] : -1;
#pragma unroll
        for (int cc = 0; cc < C_DIM; ++cc) {
            unsigned long long m = __ballot(c == cc);
            if (!m) continue;
            int leader = __ffsll(m) - 1;
            unsigned base = 0;
            if (lane == leader) base = atomicAdd(&cur[cc], (unsigned)__popcll(m));
            base = __shfl(base, leader, 64);
            if (c == cc) {
                unsigned off = __popcll(m & ((1ull << lane) - 1ull));
                idx[base + off] = i;
            }
        }
    }
}

// Convert weights to bf16, transposed for B-fragment loads:
// w1t[c][n][k] = W1[c][k][n]  (n=0..127 out col, k=0..63)
// w2t[c][n][k] = W2[c][k][n]  (n=0..127 out col, k=0..127)
__global__ void k_convert(const float* __restrict__ W1, const float* __restrict__ W2,
                          unsigned short* __restrict__ w1t, unsigned short* __restrict__ w2t) {
    int i = blockIdx.x * 256 + threadIdx.x;
    if (i < C_DIM * F_DIM * G_DIM) {
        int k = i % G_DIM, n = (i / G_DIM) % F_DIM, c = i / (G_DIM * F_DIM);
        w1t[i] = f2bf(W1[(c * G_DIM + k) * F_DIM + n]);
    }
    if (i < C_DIM * F_DIM * F_DIM) {
        int k = i % F_DIM, n = (i / F_DIM) % F_DIM, c = i / (F_DIM * F_DIM);
        w2t[i] = f2bf(W2[(c * F_DIM + k) * F_DIM + n]);
    }
}

// Main fused MLP: one block = 64 edges of a single color.
// 256 threads = 4 waves; wave w owns output cols [w*32, w*32+32).
// LDS union: A (64x72 bf16, 9216B) + H (64x136 bf16, 17408B) overlap with
// OUT staging (64x132 f32, 33792B) used only after GEMM2.
__global__ __launch_bounds__(256, 4) void mlp_main(
    const float* __restrict__ ea, const float* __restrict__ b1,
    const float* __restrict__ b2, const unsigned short* __restrict__ w1t,
    const unsigned short* __restrict__ w2t, const unsigned* __restrict__ meta,
    const int* __restrict__ idx, float* __restrict__ out) {
    __shared__ __align__(16) unsigned char smem[64 * 132 * 4];
    __shared__ int rowmap[64];
    unsigned short (*A)[72]  = (unsigned short(*)[72])smem;
    unsigned short (*H)[136] = (unsigned short(*)[136])(smem + 9216);
    float (*OUT)[132]        = (float(*)[132])smem;

    unsigned b = blockIdx.x;
    if (b >= meta[META_TSTART + C_DIM]) return;
    int c = 0;
    if (b >= meta[META_TSTART + 1]) c = 1;
    if (b >= meta[META_TSTART + 2]) c = 2;
    if (b >= meta[META_TSTART + 3]) c = 3;
    int t = (int)(b - meta[META_TSTART + c]);
    int segBase = (int)meta[META_BASES + c];
    int segCnt  = (int)meta[META_COUNTS + c];
    int row0 = t * 64;
    int nrows = segCnt - row0; if (nrows > 64) nrows = 64;

    int tid = threadIdx.x;
    if (tid < 64) rowmap[tid] = (tid < nrows) ? idx[segBase + row0 + tid] : -1;
    __syncthreads();

    // ---- stage A (gather edge rows, f32 -> bf16) ----
    {
        int r = tid >> 2, q = tid & 3;   // row, 16-float chunk
        int e = rowmap[r];
        unsigned short tmp[16];
        if (e >= 0) {
            const float4* src = (const float4*)(ea + (size_t)e * G_DIM + q * 16);
#pragma unroll
            for (int i = 0; i < 4; ++i) {
                float4 v = src[i];
                tmp[i * 4 + 0] = f2bf(v.x); tmp[i * 4 + 1] = f2bf(v.y);
                tmp[i * 4 + 2] = f2bf(v.z); tmp[i * 4 + 3] = f2bf(v.w);
            }
        } else {
#pragma unroll
            for (int i = 0; i < 16; ++i) tmp[i] = 0;
        }
        *(uint4*)&A[r][q * 16]     = *(uint4*)&tmp[0];
        *(uint4*)&A[r][q * 16 + 8] = *(uint4*)&tmp[8];
    }

    int w = tid >> 6, lane = tid & 63;
    int l15 = lane & 15, l4 = lane >> 4;

    // ---- GEMM1 weights only (keep register pressure low for occupancy) ----
    bf16x8 fB1[2][2];   // [nt][ks]
    float bias1[2];
#pragma unroll
    for (int nt = 0; nt < 2; ++nt) {
        int n = w * 32 + nt * 16 + l15;
        bias1[nt] = b1[c * F_DIM + n];
#pragma unroll
        for (int ks = 0; ks < 2; ++ks)
            fB1[nt][ks] = *(const bf16x8*)(w1t + ((size_t)(c * F_DIM + n) * G_DIM + ks * 32 + l4 * 8));
    }
    __syncthreads();  // A staged

    // ---- GEMM1: h = A @ W1 ----
    f32x4 acc[4][2];
#pragma unroll
    for (int mt = 0; mt < 4; ++mt)
#pragma unroll
        for (int nt = 0; nt < 2; ++nt) acc[mt][nt] = (f32x4){0.f, 0.f, 0.f, 0.f};
#pragma unroll
    for (int ks = 0; ks < 2; ++ks) {
#pragma unroll
        for (int mt = 0; mt < 4; ++mt) {
            bf16x8 a = *(const bf16x8*)&A[mt * 16 + l15][ks * 32 + l4 * 8];
            acc[mt][0] = __builtin_amdgcn_mfma_f32_16x16x32_bf16(a, fB1[0][ks], acc[mt][0], 0, 0, 0);
            acc[mt][1] = __builtin_amdgcn_mfma_f32_16x16x32_bf16(a, fB1[1][ks], acc[mt][1], 0, 0, 0);
        }
    }

    // ---- bias + shifted-softplus -> H (bf16) ----
#pragma unroll
    for (int mt = 0; mt < 4; ++mt)
#pragma unroll
        for (int nt = 0; nt < 2; ++nt)
#pragma unroll
            for (int r = 0; r < 4; ++r) {
                float v = acc[mt][nt][r] + bias1[nt];
                H[mt * 16 + l4 * 4 + r][w * 32 + nt * 16 + l15] = f2bf(ssp(v));
            }

    // ---- GEMM2 weights (loads overlap the barrier wait) ----
    bf16x8 fB2[2][4];
    float bias2[2];
#pragma unroll
    for (int nt = 0; nt < 2; ++nt) {
        int n = w * 32 + nt * 16 + l15;
        bias2[nt] = b2[c * F_DIM + n];
#pragma unroll
        for (int ks = 0; ks < 4; ++ks)
            fB2[nt][ks] = *(const bf16x8*)(w2t + ((size_t)(c * F_DIM + n) * F_DIM + ks * 32 + l4 * 8));
    }
    __syncthreads();  // H complete

    // ---- GEMM2: y = H @ W2 ----
#pragma unroll
    for (int mt = 0; mt < 4; ++mt)
#pragma unroll
        for (int nt = 0; nt < 2; ++nt) acc[mt][nt] = (f32x4){0.f, 0.f, 0.f, 0.f};
#pragma unroll
    for (int ks = 0; ks < 4; ++ks) {
#pragma unroll
        for (int mt = 0; mt < 4; ++mt) {
            bf16x8 a = *(const bf16x8*)&H[mt * 16 + l15][ks * 32 + l4 * 8];
            acc[mt][0] = __builtin_amdgcn_mfma_f32_16x16x32_bf16(a, fB2[0][ks], acc[mt][0], 0, 0, 0);
            acc[mt][1] = __builtin_amdgcn_mfma_f32_16x16x32_bf16(a, fB2[1][ks], acc[mt][1], 0, 0, 0);
        }
    }
    __syncthreads();  // all H reads done; smem becomes OUT staging

    // ---- bias -> OUT staging (pad 132: 2-way write conflicts = free) ----
#pragma unroll
    for (int mt = 0; mt < 4; ++mt)
#pragma unroll
        for (int r = 0; r < 4; ++r) {
            int row = mt * 16 + l4 * 4 + r;
            OUT[row][w * 32 + l15]      = acc[mt][0][r] + bias2[0];
            OUT[row][w * 32 + 16 + l15] = acc[mt][1][r] + bias2[1];
        }
    __syncthreads();

    // ---- coalesced dwordx4 stores ----
#pragma unroll
    for (int i = 0; i < 8; ++i) {
        int flat = i * 256 + tid;          // 0..2047
        int row = flat >> 5, c4 = (flat & 31) << 2;
        int e = rowmap[row];
        if (e >= 0) {
            float4 v = *(const float4*)&OUT[row][c4];
            *(float4*)(out + (size_t)e * F_DIM + c4) = v;
        }
    }
}

// Correct-but-slow fallback if ws is too small (insurance only).
__global__ void fallback(const float* __restrict__ ea, const int* __restrict__ colors,
                         const float* __restrict__ W1, const float* __restrict__ b1,
                         const float* __restrict__ W2, const float* __restrict__ b2,
                         float* __restrict__ out, int E) {
    __shared__ float sh[4][F_DIM + G_DIM];
    int w = threadIdx.x >> 6, lane = threadIdx.x & 63;
    int e = blockIdx.x * 4 + w;
    bool valid = (e < E);
    int ec = valid ? e : 0;
    int c = colors[ec];
    float* hv = sh[w];
    float* av = sh[w] + F_DIM;
    av[lane] = ea[(size_t)ec * G_DIM + lane];
    __syncthreads();
    for (int f = lane; f < F_DIM; f += 64) {
        float s = b1[c * F_DIM + f];
        for (int g = 0; g < G_DIM; ++g) s += av[g] * W1[(c * G_DIM + g) * F_DIM + f];
        hv[f] = ssp(s);
    }
    __syncthreads();
    for (int f = lane; f < F_DIM; f += 64) {
        float s = b2[c * F_DIM + f];
        for (int k = 0; k < F_DIM; ++k) s += hv[k] * W2[(c * F_DIM + k) * F_DIM + f];
        if (valid) out[(size_t)e * F_DIM + f] = s;
    }
}

extern "C" void kernel_launch(void* const* d_in, const int* in_sizes, int n_in,
                              void* d_out, int out_size, void* d_ws, size_t ws_size,
                              hipStream_t stream) {
    const float* ea     = (const float*)d_in[0];
    const int*   colors = (const int*)d_in[1];
    const float* W1     = (const float*)d_in[2];
    const float* b1     = (const float*)d_in[3];
    const float* W2     = (const float*)d_in[4];
    const float* b2     = (const float*)d_in[5];
    float* out = (float*)d_out;
    int E = in_sizes[1];

    size_t need = (size_t)(IDX_OFF + E) * 4 +
                  (size_t)(C_DIM * F_DIM * G_DIM + C_DIM * F_DIM * F_DIM) * 2;
    if (ws_size < need) {
        int blocks = (E + 3) / 4;
        fallback<<<blocks, 256, 0, stream>>>(ea, colors, W1, b1, W2, b2, out, E);
        return;
    }

    unsigned* meta = (unsigned*)d_ws;
    unsigned* bh   = (unsigned*)d_ws + BH_OFF;
    int* idx = (int*)d_ws + IDX_OFF;
    unsigned short* w1t = (unsigned short*)((char*)d_ws + (size_t)(IDX_OFF + E) * 4);
    unsigned short* w2t = w1t + C_DIM * F_DIM * G_DIM;

    int CH = (E + NB - 1) / NB;
    k_hist<<<NB, 256, 0, stream>>>(colors, E, CH, bh);
    k_scan<<<1, 256, 0, stream>>>(meta, bh);
    k_convert<<<256, 256, 0, stream>>>(W1, W2, w1t, w2t);
    k_scatter2<<<NB, 256, 0, stream>>>(colors, E, CH, bh, idx);
    int g4 = (E + 63) / 64 + C_DIM;
    mlp_main<<<g4, 256, 0, stream>>>(ea, b1, b2, w1t, w2t, meta, idx, out);
}